// Round 12
// baseline (274.193 us; speedup 1.0000x reference)
//
#include <hip/hip_runtime.h>

typedef __attribute__((ext_vector_type(8))) short bf16x8;
typedef __attribute__((ext_vector_type(4))) float f32x4;
typedef __attribute__((ext_vector_type(8))) unsigned short ushort8;
typedef __attribute__((ext_vector_type(4))) unsigned short ushort4v;
typedef __attribute__((ext_vector_type(4))) float float4v;
typedef __attribute__((ext_vector_type(2))) unsigned int uint2v;
typedef __attribute__((ext_vector_type(4))) unsigned int uint4v;

#define TGT 256
#define BSZ 64
#define EMB 1024
#define NH 16
#define HD 64
#define PP 16

__device__ __forceinline__ float b2f(unsigned short u) {
  return __builtin_bit_cast(float, ((unsigned int)u) << 16);
}
__device__ __forceinline__ unsigned short f2b(float f) {
  unsigned int u = __builtin_bit_cast(unsigned int, f);
  u += 0x7fffu + ((u >> 16) & 1u);  // RNE; no NaNs in this workload
  return (unsigned short)(u >> 16);
}
__device__ __forceinline__ unsigned int pack2(float lo, float hi) {
  return (unsigned int)f2b(lo) | ((unsigned int)f2b(hi) << 16);
}
__device__ __forceinline__ f32x4 mfma16(bf16x8 a, bf16x8 b, f32x4 c) {
  return __builtin_amdgcn_mfma_f32_16x16x32_bf16(a, b, c, 0, 0, 0);
}
// async global->LDS, 16B per lane; LDS dest is wave-uniform base + lane*16
__device__ __forceinline__ void gl_lds16(const unsigned short* g, unsigned short* l) {
  __builtin_amdgcn_global_load_lds(
      (const __attribute__((address_space(1))) unsigned int*)g,
      (__attribute__((address_space(3))) unsigned int*)l, 16, 0, 0);
}

// ---------------------------------------------------------------------------
// Gate: g1[b] = softmax((feat[b]@gw.T + gb + noise[b]) / 3)[1]
// ---------------------------------------------------------------------------
__global__ __launch_bounds__(64) void gate_kernel(
    const float* __restrict__ feat, const float* __restrict__ gw,
    const float* __restrict__ gb, const float* __restrict__ noise,
    float* __restrict__ g1) {
  const int b = blockIdx.x, lane = threadIdx.x;
  float a0 = 0.f, a1 = 0.f;
  for (int i = lane; i < 512; i += 64) {
    float f = feat[b * 512 + i];
    a0 += f * gw[i];
    a1 += f * gw[512 + i];
  }
#pragma unroll
  for (int off = 32; off >= 1; off >>= 1) {
    a0 += __shfl_xor(a0, off);
    a1 += __shfl_xor(a1, off);
  }
  if (lane == 0) {
    float l0 = (a0 + gb[0] + noise[b * 2 + 0]) * (1.0f / 3.0f);
    float l1 = (a1 + gb[1] + noise[b * 2 + 1]) * (1.0f / 3.0f);
    float mm = fmaxf(l0, l1);
    float e0 = __expf(l0 - mm), e1 = __expf(l1 - mm);
    g1[b] = e1 / (e0 + e1);
  }
}

// ---------------------------------------------------------------------------
// f32 -> bf16 cast, 8 elems/thread, grid-stride (weights only now)
// ---------------------------------------------------------------------------
__global__ __launch_bounds__(256) void cast_bf16_kernel(
    const float* __restrict__ in, unsigned short* __restrict__ out, int n8) {
  int i = blockIdx.x * blockDim.x + threadIdx.x;
  const int stride = gridDim.x * blockDim.x;
  for (; i < n8; i += stride) {
    const float4v* p = (const float4v*)(in + (size_t)i * 8);
    float4v v0 = p[0], v1 = p[1];
    ushort8 o = {f2b(v0[0]), f2b(v0[1]), f2b(v0[2]), f2b(v0[3]),
                 f2b(v1[0]), f2b(v1[1]), f2b(v1[2]), f2b(v1[3])};
    *(ushort8*)(out + (size_t)i * 8) = o;
  }
}

// ---------------------------------------------------------------------------
// gemm128f: projections. C_bf16_headblocked[16384,1024] = A_f32 @ W_bf16^T + b
// BM=128 x BN=256, grid 512 WGs -> 2 blocks/CU (LDS 80KB exactly); 8 waves
// (2Mx4N), per-wave 64x64 (acc 4x4). B: gl_lds lead-3 ring-4 (R4-proven
// schedule, unchanged). A: reg-staged f32 lead-2 ring-2 (R11-proven anchor):
// issue A(s+2) in phase 1; f2b + swizzled ds_write_b128 of A(s+1) at step
// end -- the COMPILER-exact vmcnt before the f2b completes A(s+1) and
// (oldest-first) everything older incl. B(s+1). Manual vmcnt(6) backstop =
// steady outstanding {B(s+2),A(s+2),B(s+3)} = 2+2+2. lgkmcnt(0)+barrier
// publishes the ds_write. 2 blocks/CU gives the TLP that R11's 1-block/CU
// 256x256 grid lacked (OccupancyPercent 19%, all pipes <25%).
// QSCALE folds attention 1/sqrt(d)=0.125 into the q-projection output.
// ---------------------------------------------------------------------------
#define A128_ISSUE(t)                                    \
  {                                                      \
    const float* _p = a32p + (size_t)(t) * 32;           \
    ar[(t) & 1][0] = *(const float4v*)_p;                \
    ar[(t) & 1][1] = *(const float4v*)(_p + 4);          \
  }
#define A128_WRITE(t)                                                   \
  {                                                                     \
    float4v* v = ar[(t) & 1];                                           \
    uint4v h = {pack2(v[0][0], v[0][1]), pack2(v[0][2], v[0][3]),       \
                pack2(v[1][0], v[1][1]), pack2(v[1][2], v[1][3])};      \
    *(uint4v*)&As[(t) & 1][swA] = h;                                    \
  }
#define B128_STAGE(s)                                    \
  {                                                      \
    int k0s = (s) * 32;                                  \
    unsigned short* d = &Bs[(s) & 3][wl];                \
    gl_lds16(b0p + k0s, d);                              \
    gl_lds16(b1p + k0s, d + 4096);                       \
  }
#define G128_STEP(s, DO_IA, DO_SB, DO_W)                              \
  {                                                                   \
    const unsigned short* Ab = &As[(s) & 1][0];                       \
    const unsigned short* Bb = &Bs[(s) & 3][0];                       \
    bf16x8 af[4], bfr[4];                                             \
    _Pragma("unroll") for (int mi = 0; mi < 4; ++mi)                  \
        af[mi] = *(const bf16x8*)&Ab[aoff + mi * 512];                \
    _Pragma("unroll") for (int ni = 0; ni < 2; ++ni)                  \
        bfr[ni] = *(const bf16x8*)&Bb[boff + ni * 512];               \
    if (DO_IA) A128_ISSUE((s) + 2);                                   \
    __builtin_amdgcn_s_barrier();                                     \
    __builtin_amdgcn_s_setprio(1);                                    \
    _Pragma("unroll") for (int mi = 0; mi < 4; ++mi) {                \
      acc[mi][0] = mfma16(af[mi], bfr[0], acc[mi][0]);                \
      acc[mi][1] = mfma16(af[mi], bfr[1], acc[mi][1]);                \
    }                                                                 \
    __builtin_amdgcn_s_setprio(0);                                    \
    __builtin_amdgcn_s_barrier();                                     \
    _Pragma("unroll") for (int ni = 2; ni < 4; ++ni)                  \
        bfr[ni] = *(const bf16x8*)&Bb[boff + ni * 512];               \
    if (DO_SB) B128_STAGE((s) + 3);                                   \
    __builtin_amdgcn_s_barrier();                                     \
    __builtin_amdgcn_s_setprio(1);                                    \
    _Pragma("unroll") for (int mi = 0; mi < 4; ++mi) {                \
      acc[mi][2] = mfma16(af[mi], bfr[2], acc[mi][2]);                \
      acc[mi][3] = mfma16(af[mi], bfr[3], acc[mi][3]);                \
    }                                                                 \
    __builtin_amdgcn_s_setprio(0);                                    \
    if (DO_W) A128_WRITE((s) + 1);                                    \
  }
#define STEP_WAIT(cntstr)                                \
  asm volatile("s_waitcnt " cntstr ::: "memory");        \
  __builtin_amdgcn_sched_barrier(0);                     \
  __builtin_amdgcn_s_barrier();

template <int QSCALE>
__global__ __launch_bounds__(512, 4) void gemm128f_kernel(
    const float* __restrict__ A, const unsigned short* __restrict__ W,
    const float* __restrict__ bias, unsigned short* __restrict__ Cv) {
  constexpr int K = 1024, N = 1024;
  __shared__ __attribute__((aligned(16))) unsigned short As[2][4096];  // 16 KB
  __shared__ __attribute__((aligned(16))) unsigned short Bs[4][8192];  // 64 KB
  const int tid = threadIdx.x;
  const int wv = tid >> 6, lane = tid & 63;
  const int l15 = lane & 15, kg = lane >> 4;
  const int bid = blockIdx.x;
  const int cpx = gridDim.x >> 3;  // 64, nwg=512 divisible by 8
  const int wg = (bid & 7) * cpx + (bid >> 3);
  const int m0 = (wg >> 2) * 128, n0 = (wg & 3) * 256;
  const int wmL = (wv >> 2) * 64, wnL = (wv & 3) * 64;

  // B staging geometry (identical to proven gemm256): wave stages 16 rows/half
  const int sr = wv * 16 + (lane >> 2);
  const int sc = ((lane & 3) * 8) ^ (((sr >> 1) & 3) << 3);  // pre-swizzled col
  const unsigned short* b0p = W + (size_t)(n0 + sr) * K + sc;
  const unsigned short* b1p = b0p + (size_t)128 * K;
  const int wl = wv * 512;

  // A reg staging: thread covers row tid>>2 (0..127), cols (tid&3)*8..+8
  const int arr = tid >> 2;
  const float* a32p = A + (size_t)(m0 + arr) * K + (tid & 3) * 8;
  const int swA = arr * 32 + (((tid & 3) ^ ((arr >> 1) & 3)) << 3);
  float4v ar[2][2];  // lead-2 ring (16 VGPR, literal-indexed)

  // read addressing; (row>>1)&3 == (l15>>1)&3 since wmL, mi*16 are 0 mod 4
  // after >>1
  const int x = ((l15 >> 1) & 3) << 3;
  const int aoff = (wmL + l15) * 32 + ((kg * 8) ^ x);
  const int boff = (wnL + l15) * 32 + ((kg * 8) ^ x);

  f32x4 acc[4][4];
#pragma unroll
  for (int i = 0; i < 4; ++i)
#pragma unroll
    for (int j = 0; j < 4; ++j) acc[i][j] = (f32x4){0.f, 0.f, 0.f, 0.f};

  // Prologue. After A128_WRITE(0)'s compiler wait (drains A(0)),
  // outstanding = B(0)2 + A(1)2 + B(1)2 + B(2)2 = 8; vmcnt(6) completes B(0).
  A128_ISSUE(0); B128_STAGE(0); A128_ISSUE(1); B128_STAGE(1); B128_STAGE(2);
  A128_WRITE(0);
  STEP_WAIT("vmcnt(6) lgkmcnt(0)")

#pragma unroll
  for (int s = 0; s < 30; ++s) {
    G128_STEP(s, (s < 30), (s < 29), 1);
    STEP_WAIT("vmcnt(6) lgkmcnt(0)")
  }
  G128_STEP(30, 0, 0, 1);  // writes A(31); compiler wait drains A(31)
  STEP_WAIT("vmcnt(0) lgkmcnt(0)")
  G128_STEP(31, 0, 0, 0);

#pragma unroll
  for (int mi = 0; mi < 4; ++mi) {
#pragma unroll
    for (int ni = 0; ni < 4; ++ni) {
      int col = n0 + wnL + ni * 16 + l15;
      float bcol = bias[col];
#pragma unroll
      for (int r = 0; r < 4; ++r) {
        int row = m0 + wmL + mi * 16 + kg * 4 + r;
        float v = acc[mi][ni][r] + bcol;
        if constexpr (QSCALE) v *= 0.125f;
        // head-blocked store: [(b*16+h)][t][d]
        int t = row >> 6, bb = row & 63, hh = col >> 6, dd = col & 63;
        Cv[(size_t)((bb * 16 + hh) * 256 + t) * 64 + dd] = f2b(v);
      }
    }
  }
}

// ---------------------------------------------------------------------------
// gemm256: out-projection only (proven R4 gl_lds path, bf16 A head-blocked).
// 256x256 tile, 8 waves, BK=32; counted-vmcnt; LDS XOR swizzle; setprio;
// XCD-chunked swizzle. A_BLOCKED reads head-blocked [(b*16+h)][t][d];
// OUT_F32 writes row-major f32.
// ---------------------------------------------------------------------------
#define AOFF(s) (((s) >> 1) * 16384 + ((s)&1) * 32)
#define STAGE_A(s)                                       \
  {                                                      \
    const unsigned short* _ap = abf + AOFF(s);           \
    unsigned short* d = &As[(s) & 3][wl];                \
    gl_lds16(_ap, d);                                    \
    gl_lds16(_ap + 128, d + 4096);                       \
  }
#define STAGE_B(s)                                       \
  {                                                      \
    int k0s = (s) * 32;                                  \
    unsigned short* d = &Bs[(s) & 3][wl];                \
    gl_lds16(b0p + k0s, d);                              \
    gl_lds16(b1p + k0s, d + 4096);                       \
  }
#define GEMM_STEP(s, DO_STAGE)                                        \
  {                                                                   \
    const unsigned short* Ab = &As[(s) & 3][0];                       \
    const unsigned short* Bb = &Bs[(s) & 3][0];                       \
    bf16x8 af[8], bfr[4];                                             \
    _Pragma("unroll") for (int mi = 0; mi < 8; ++mi)                  \
        af[mi] = *(const bf16x8*)&Ab[aoff + mi * 512];                \
    _Pragma("unroll") for (int ni = 0; ni < 2; ++ni)                  \
        bfr[ni] = *(const bf16x8*)&Bb[boff + ni * 512];               \
    if (DO_STAGE) STAGE_A((s) + 3);                                   \
    __builtin_amdgcn_s_barrier();                                     \
    __builtin_amdgcn_s_setprio(1);                                    \
    _Pragma("unroll") for (int mi = 0; mi < 8; ++mi) {                \
      acc[mi][0] = mfma16(af[mi], bfr[0], acc[mi][0]);                \
      acc[mi][1] = mfma16(af[mi], bfr[1], acc[mi][1]);                \
    }                                                                 \
    __builtin_amdgcn_s_setprio(0);                                    \
    __builtin_amdgcn_s_barrier();                                     \
    _Pragma("unroll") for (int ni = 2; ni < 4; ++ni)                  \
        bfr[ni] = *(const bf16x8*)&Bb[boff + ni * 512];               \
    if (DO_STAGE) STAGE_B((s) + 3);                                   \
    __builtin_amdgcn_s_barrier();                                     \
    __builtin_amdgcn_s_setprio(1);                                    \
    _Pragma("unroll") for (int mi = 0; mi < 8; ++mi) {                \
      acc[mi][2] = mfma16(af[mi], bfr[2], acc[mi][2]);                \
      acc[mi][3] = mfma16(af[mi], bfr[3], acc[mi][3]);                \
    }                                                                 \
    __builtin_amdgcn_s_setprio(0);                                    \
  }

__global__ __launch_bounds__(512, 2) void gemm256_kernel(
    const unsigned short* __restrict__ A, const unsigned short* __restrict__ W,
    const float* __restrict__ bias, float* __restrict__ Cv) {
  constexpr int K = 1024, N = 1024;
  __shared__ __attribute__((aligned(16))) unsigned short As[4][8192];  // 64 KB
  __shared__ __attribute__((aligned(16))) unsigned short Bs[4][8192];  // 64 KB
  const int tid = threadIdx.x;
  const int wv = tid >> 6, lane = tid & 63;
  const int l15 = lane & 15, kg = lane >> 4;
  const int bid = blockIdx.x;
  const int cpx = gridDim.x >> 3;
  const int wg = (bid & 7) * cpx + (bid >> 3);
  const int m0 = (wg >> 2) * 256, n0 = (wg & 3) * 256;
  const int wmL = (wv >> 2) * 128, wnL = (wv & 3) * 64;

  const int sr = wv * 16 + (lane >> 2);                      // row in 128-half
  const int sc = ((lane & 3) * 8) ^ (((sr >> 1) & 3) << 3);  // pre-swizzled col
  const int srg = m0 + sr;
  const unsigned short* abf =
      A + (size_t)(srg & 63) * 262144 + (srg >> 6) * 64 + sc;  // head-blocked
  const unsigned short* b0p = W + (size_t)(n0 + sr) * K + sc;
  const unsigned short* b1p = b0p + (size_t)128 * K;
  const int wl = wv * 512;

  const int x = ((l15 >> 1) & 3) << 3;
  const int aoff = (wmL + l15) * 32 + ((kg * 8) ^ x);
  const int boff = (wnL + l15) * 32 + ((kg * 8) ^ x);

  f32x4 acc[8][4];
#pragma unroll
  for (int i = 0; i < 8; ++i)
#pragma unroll
    for (int j = 0; j < 4; ++j) acc[i][j] = (f32x4){0.f, 0.f, 0.f, 0.f};

  STAGE_A(0); STAGE_B(0); STAGE_A(1); STAGE_B(1); STAGE_A(2); STAGE_B(2);
  STEP_WAIT("vmcnt(8)")

  for (int s = 0; s < 29; ++s) {
    GEMM_STEP(s, 1);
    STEP_WAIT("vmcnt(8)")
  }
  GEMM_STEP(29, 0);
  STEP_WAIT("vmcnt(4)")
  GEMM_STEP(30, 0);
  STEP_WAIT("vmcnt(0)")
  GEMM_STEP(31, 0);

#pragma unroll
  for (int mi = 0; mi < 8; ++mi) {
#pragma unroll
    for (int ni = 0; ni < 4; ++ni) {
      int col = n0 + wnL + ni * 16 + l15;
      float bcol = bias[col];
#pragma unroll
      for (int r = 0; r < 4; ++r) {
        int row = m0 + wmL + mi * 16 + kg * 4 + r;
        Cv[(size_t)row * N + col] = acc[mi][ni][r] + bcol;
      }
    }
  }
}

// ---------------------------------------------------------------------------
// MFMA attention per (b,h) — EXACT R4-proven kernel.
// q/k/v/comb HEAD-BLOCKED [(b*16+h)][t][d]; 8 waves x 32 t-rows,
// strip-merged; natural-log softmax via __expf; pack2/f2b packing;
// T13 defer-rescale; V^T gran swizzle.
// combined = attn + g1[t>>2]*bw[b]*attn_pre (uses g0+g1==1).
// Q pre-scaled by 0.125 in the q-projection GEMM.
// ---------------------------------------------------------------------------
__global__ __launch_bounds__(512) void attn_kernel(
    const unsigned short* __restrict__ qb, const unsigned short* __restrict__ kb,
    const unsigned short* __restrict__ vb, const float* __restrict__ prefix,
    const float* __restrict__ bw, const float* __restrict__ g1,
    unsigned short* __restrict__ comb) {
  const int b = blockIdx.x, h = blockIdx.y;
  __shared__ __attribute__((aligned(16))) unsigned short Kl[256][64];    // 32 KB, chunk-XOR
  __shared__ __attribute__((aligned(16))) unsigned short Vt[64 * 256];   // 32 KB, V^T swizzled
  __shared__ __attribute__((aligned(16))) unsigned short PKl[16][64];    // 2 KB, chunk-XOR
  __shared__ __attribute__((aligned(16))) unsigned short PVt[64][32];    // 4 KB
  __shared__ __attribute__((aligned(16))) unsigned short Plds[8][16][40];// 10 KB, per-wave P
  unsigned short* Cb = &Kl[0][0];  // output bounce overlays Kl
  const int tid = threadIdx.x;
  const int wv = tid >> 6, lane = tid & 63;
  const size_t slab = (size_t)(b * NH + h) * 16384;

  // ---- staging (coalesced slab reads) ----
#pragma unroll
  for (int it = 0; it < 4; ++it) {
    int cid = tid + it * 512;
    int j = cid >> 3, c = cid & 7;  // j = s row, c = d-chunk
    gl_lds16(kb + slab + (size_t)j * 64 + ((c ^ (j & 7)) << 3),
             &Kl[0][0] + (size_t)(it * 512 + wv * 64) * 8);
    ushort8 vv = *(const ushort8*)(vb + slab + (size_t)j * 64 + (c << 3));
#pragma unroll
    for (int i = 0; i < 8; ++i) {  // V^T: (d=c*8+i, s=j); gran = (s>>3)^(d&7)^(d>>3)
      int gran = (j >> 3) ^ i ^ c;
      Vt[(c * 8 + i) * 256 + gran * 8 + (j & 7)] = vv[i];
    }
  }
  if (tid < 256) {
    int arr = tid >> 7, cid = tid & 127;
    int sp = cid >> 3, c = cid & 7;
    const float* src = prefix + ((size_t)(b * 2 + arr) * PP + sp) * EMB + h * HD + c * 8;
    float4v v0 = *(const float4v*)src;
    float4v v1 = *(const float4v*)(src + 4);
    if (arr == 0) {
      ushort8 o = {f2b(v0[0]), f2b(v0[1]), f2b(v0[2]), f2b(v0[3]),
                   f2b(v1[0]), f2b(v1[1]), f2b(v1[2]), f2b(v1[3])};
      *(ushort8*)&PKl[sp][((c ^ (sp & 7)) << 3)] = o;
    } else {
#pragma unroll
      for (int i = 0; i < 8; ++i)
        PVt[c * 8 + i][sp] = f2b(i < 4 ? v0[i] : v1[i - 4]);
    }
  } else if (tid < 384) {
    int cid = tid - 256;
    *(ushort8*)&PVt[cid >> 1][16 + (cid & 1) * 8] = (ushort8){0, 0, 0, 0, 0, 0, 0, 0};
  }
  __syncthreads();

  const int l15 = lane & 15, g = lane >> 4;
  const int swl = l15 & 7;
  const float bwb = bw[b];
  unsigned short(&Pw)[16][40] = Plds[wv];

  const int t0 = wv * 32 + l15;  // strip-0 row; strip-1 = t0+16
  const size_t qbase = slab + (size_t)t0 * 64;
  bf16x8 qf[2][2];
  qf[0][0] = *(const bf16x8*)(qb + qbase + g * 8);
  qf[0][1] = *(const bf16x8*)(qb + qbase + 32 + g * 8);
  qf[1][0] = *(const bf16x8*)(qb + qbase + 1024 + g * 8);
  qf[1][1] = *(const bf16x8*)(qb + qbase + 1024 + 32 + g * 8);

  f32x4 O[2][4];
#pragma unroll
  for (int st = 0; st < 2; ++st)
#pragma unroll
    for (int dt = 0; dt < 4; ++dt) O[st][dt] = (f32x4){0.f, 0.f, 0.f, 0.f};
  float m[2] = {-3.0e38f, -3.0e38f}, l[2] = {0.f, 0.f};

#pragma unroll
  for (int ch = 0; ch < 8; ++ch) {  // 32 s per chunk
    const int rA = ch * 32 + l15, rB = rA + 16;
    bf16x8 ka0 = *(const bf16x8*)&Kl[rA][((g ^ swl) << 3)];
    bf16x8 ka1 = *(const bf16x8*)&Kl[rA][(((4 + g) ^ swl) << 3)];
    bf16x8 kb0 = *(const bf16x8*)&Kl[rB][((g ^ swl) << 3)];
    bf16x8 kb1 = *(const bf16x8*)&Kl[rB][(((4 + g) ^ swl) << 3)];
    f32x4 s[2][2];
#pragma unroll
    for (int st = 0; st < 2; ++st) {
      s[st][0] = (f32x4){0.f, 0.f, 0.f, 0.f};
      s[st][1] = (f32x4){0.f, 0.f, 0.f, 0.f};
      s[st][0] = mfma16(ka0, qf[st][0], s[st][0]);
      s[st][0] = mfma16(ka1, qf[st][1], s[st][0]);
      s[st][1] = mfma16(kb0, qf[st][0], s[st][1]);
      s[st][1] = mfma16(kb1, qf[st][1], s[st][1]);
    }
    bf16x8 pf[2];
#pragma unroll
    for (int st = 0; st < 2; ++st) {
      f32x4 sa = s[st][0], sb = s[st][1];
      float mx = fmaxf(fmaxf(fmaxf(sa[0], sa[1]), fmaxf(sa[2], sa[3])),
                       fmaxf(fmaxf(sb[0], sb[1]), fmaxf(sb[2], sb[3])));
      mx = fmaxf(mx, __shfl_xor(mx, 16));
      mx = fmaxf(mx, __shfl_xor(mx, 32));
      // T13 defer-rescale: only rescale when some row grew by > 8
      if (__ballot(mx > m[st] + 8.0f) != 0ull) {
        float mn = fmaxf(m[st], mx);
        float f = __expf(m[st] - mn);
        m[st] = mn;
        l[st] *= f;
#pragma unroll
        for (int dt = 0; dt < 4; ++dt)
#pragma unroll
          for (int r = 0; r < 4; ++r) O[st][dt][r] *= f;
      }
      float pA[4], pB[4];
#pragma unroll
      for (int r = 0; r < 4; ++r) {
        pA[r] = __expf(sa[r] - m[st]);
        pB[r] = __expf(sb[r] - m[st]);
      }
      uint2v wa = {pack2(pA[0], pA[1]), pack2(pA[2], pA[3])};
      uint2v wb2 = {pack2(pB[0], pB[1]), pack2(pB[2], pB[3])};
      *(uint2v*)&Pw[l15][g * 4] = wa;
      *(uint2v*)&Pw[l15][16 + g * 4] = wb2;
      // l accumulates the ROUNDED p so normalization compensates quantization
      float sloc = b2f((unsigned short)(wa[0] & 0xffff)) + b2f((unsigned short)(wa[0] >> 16)) +
                   b2f((unsigned short)(wa[1] & 0xffff)) + b2f((unsigned short)(wa[1] >> 16)) +
                   b2f((unsigned short)(wb2[0] & 0xffff)) + b2f((unsigned short)(wb2[0] >> 16)) +
                   b2f((unsigned short)(wb2[1] & 0xffff)) + b2f((unsigned short)(wb2[1] >> 16));
      l[st] += sloc;
      // read own B-frag before next strip overwrites the tile (in-order DS)
      pf[st] = *(const bf16x8*)&Pw[l15][g * 8];
    }
#pragma unroll
    for (int dt = 0; dt < 4; ++dt) {
      const int drow = dt * 16 + l15;
      const int gran = (ch * 4 + g) ^ (drow & 7) ^ (drow >> 3);
      bf16x8 vf = *(const bf16x8*)&Vt[drow * 256 + gran * 8];
      O[0][dt] = mfma16(vf, pf[0], O[0][dt]);
      O[1][dt] = mfma16(vf, pf[1], O[1][dt]);
    }
  }

#pragma unroll
  for (int st = 0; st < 2; ++st) {
    float lf = l[st];
    lf += __shfl_xor(lf, 16);
    lf += __shfl_xor(lf, 32);
    float inv = 1.0f / lf;
#pragma unroll
    for (int dt = 0; dt < 4; ++dt)
#pragma unroll
      for (int r = 0; r < 4; ++r) O[st][dt][r] *= inv;
  }

  // prefix attention (s=16 zero-padded to 32), scaled by g1*bw/sum
  {
    bf16x8 pk0 = *(const bf16x8*)&PKl[l15][((g ^ swl) << 3)];
    bf16x8 pk1 = *(const bf16x8*)&PKl[l15][(((4 + g) ^ swl) << 3)];
    bf16x8 ppf[2];
#pragma unroll
    for (int st = 0; st < 2; ++st) {
      f32x4 sp4 = (f32x4){0.f, 0.f, 0.f, 0.f};
      sp4 = mfma16(pk0, qf[st][0], sp4);
      sp4 = mfma16(pk1, qf[st][1], sp4);
      float pm = fmaxf(fmaxf(sp4[0], sp4[1]), fmaxf(sp4[2], sp4[3]));
      pm = fmaxf(pm, __shfl_xor(pm, 16));
      pm = fmaxf(pm, __shfl_xor(pm, 32));
      float pe[4], pl = 0.f;
#pragma unroll
      for (int r = 0; r < 4; ++r) {
        pe[r] = __expf(sp4[r] - pm);
        pl += pe[r];
      }
      pl += __shfl_xor(pl, 16);
      pl += __shfl_xor(pl, 32);
      float cpre = g1[(t0 + 16 * st) >> 2] * bwb / pl;
#pragma unroll
      for (int r = 0; r < 4; ++r) pe[r] *= cpre;
      *(uint2v*)&Pw[l15][g * 4] = (uint2v){pack2(pe[0], pe[1]), pack2(pe[2], pe[3])};
      *(uint2v*)&Pw[l15][16 + g * 4] = (uint2v){0u, 0u};
      ppf[st] = *(const bf16x8*)&Pw[l15][g * 8];
    }
#pragma unroll
    for (int dt = 0; dt < 4; ++dt) {
      bf16x8 pvf = *(const bf16x8*)&PVt[dt * 16 + l15][g * 8];
      O[0][dt] = mfma16(pvf, ppf[0], O[0][dt]);
      O[1][dt] = mfma16(pvf, ppf[1], O[1][dt]);
    }
  }

  __syncthreads();  // all waves done reading Kl before bounce overlays it
#pragma unroll
  for (int st = 0; st < 2; ++st) {
    int t = wv * 32 + st * 16 + l15;
#pragma unroll
    for (int dt = 0; dt < 4; ++dt) {
#pragma unroll
      for (int u = 0; u < 2; ++u) {
        unsigned int pw = pack2(O[st][dt][2 * u], O[st][dt][2 * u + 1]);
        int d = dt * 16 + g * 4 + 2 * u;
        *(unsigned int*)&Cb[t * 64 + (((d >> 3) ^ (t & 7)) << 3) + (d & 7)] = pw;
      }
    }
  }
  __syncthreads();
#pragma unroll
  for (int it = 0; it < 4; ++it) {
    int cid = tid + it * 512;
    int j = cid >> 3, c = cid & 7;
    ushort8 row = *(const ushort8*)&Cb[j * 64 + ((c ^ (j & 7)) << 3)];
    *(ushort8*)(comb + slab + (size_t)j * 64 + (c << 3)) = row;
  }
}

// ---------------------------------------------------------------------------
extern "C" void kernel_launch(void* const* d_in, const int* in_sizes, int n_in,
                              void* d_out, int out_size, void* d_ws, size_t ws_size,
                              hipStream_t stream) {
  const float* query = (const float*)d_in[1];
  const float* key = (const float*)d_in[2];
  const float* value = (const float*)d_in[3];
  const float* prefix = (const float*)d_in[4];
  const float* bw = (const float*)d_in[5];
  const float* feat = (const float*)d_in[6];
  const float* noise = (const float*)d_in[7];
  const float* ipw = (const float*)d_in[8];
  const float* ipb = (const float*)d_in[9];
  const float* outw = (const float*)d_in[10];
  const float* outb = (const float*)d_in[11];
  const float* gw = (const float*)d_in[12];
  const float* gb = (const float*)d_in[13];
  float* out = (float*)d_out;

  char* ws = (char*)d_ws;
  const size_t MATB = (size_t)16384 * 1024;  // elements per [16384,1024] matrix
  unsigned short* qb = (unsigned short*)ws;
  unsigned short* kb = qb + MATB;
  unsigned short* vb = kb + MATB;
  unsigned short* cb = vb + MATB;            // attn output (head-blocked)
  unsigned short* wip = cb + MATB;           // bf16 in_proj_w [3072,1024]
  unsigned short* wo = wip + (size_t)3072 * 1024;  // bf16 out_w [1024,1024]
  float* g1 = (float*)(wo + (size_t)1024 * 1024);

  gate_kernel<<<64, 64, 0, stream>>>(feat, gw, gb, noise, g1);

  // weight casts only (16.8 MB total)
  cast_bf16_kernel<<<1536, 256, 0, stream>>>(ipw, wip, 3072 * 1024 / 8);
  cast_bf16_kernel<<<512, 256, 0, stream>>>(outw, wo, 1024 * 1024 / 8);

  // projections: f32 A direct, 128x256 tiles, 2 blocks/CU
  gemm128f_kernel<1><<<512, 512, 0, stream>>>(query, wip, ipb, qb);
  gemm128f_kernel<0><<<512, 512, 0, stream>>>(key, wip + (size_t)1024 * 1024, ipb + 1024, kb);
  gemm128f_kernel<0><<<512, 512, 0, stream>>>(value, wip + (size_t)2048 * 1024, ipb + 2048, vb);

  attn_kernel<<<dim3(64, 16), 512, 0, stream>>>(qb, kb, vb, prefix, bw, g1, cb);

  // out-projection reads head-blocked bf16 attn output (proven gl_lds path)
  gemm256_kernel<<<256, 512, 0, stream>>>(cb, wo, outb, out);
}

// Round 13
// 258.569 us; speedup vs baseline: 1.0604x; 1.0604x over previous
//
#include <hip/hip_runtime.h>

typedef __attribute__((ext_vector_type(8))) short bf16x8;
typedef __attribute__((ext_vector_type(4))) float f32x4;
typedef __attribute__((ext_vector_type(8))) unsigned short ushort8;
typedef __attribute__((ext_vector_type(4))) unsigned short ushort4v;
typedef __attribute__((ext_vector_type(4))) float float4v;
typedef __attribute__((ext_vector_type(2))) unsigned int uint2v;
typedef __attribute__((ext_vector_type(4))) unsigned int uint4v;

#define TGT 256
#define BSZ 64
#define EMB 1024
#define NH 16
#define HD 64
#define PP 16

__device__ __forceinline__ float b2f(unsigned short u) {
  return __builtin_bit_cast(float, ((unsigned int)u) << 16);
}
__device__ __forceinline__ unsigned short f2b(float f) {
  unsigned int u = __builtin_bit_cast(unsigned int, f);
  u += 0x7fffu + ((u >> 16) & 1u);  // RNE; no NaNs in this workload
  return (unsigned short)(u >> 16);
}
__device__ __forceinline__ unsigned int pack2(float lo, float hi) {
  return (unsigned int)f2b(lo) | ((unsigned int)f2b(hi) << 16);
}
__device__ __forceinline__ f32x4 mfma16(bf16x8 a, bf16x8 b, f32x4 c) {
  return __builtin_amdgcn_mfma_f32_16x16x32_bf16(a, b, c, 0, 0, 0);
}
// async global->LDS, 16B per lane; LDS dest is wave-uniform base + lane*16
__device__ __forceinline__ void gl_lds16(const unsigned short* g, unsigned short* l) {
  __builtin_amdgcn_global_load_lds(
      (const __attribute__((address_space(1))) unsigned int*)g,
      (__attribute__((address_space(3))) unsigned int*)l, 16, 0, 0);
}

// ---------------------------------------------------------------------------
// Gate: g1[b] = softmax((feat[b]@gw.T + gb + noise[b]) / 3)[1]
// ---------------------------------------------------------------------------
__global__ __launch_bounds__(64) void gate_kernel(
    const float* __restrict__ feat, const float* __restrict__ gw,
    const float* __restrict__ gb, const float* __restrict__ noise,
    float* __restrict__ g1) {
  const int b = blockIdx.x, lane = threadIdx.x;
  float a0 = 0.f, a1 = 0.f;
  for (int i = lane; i < 512; i += 64) {
    float f = feat[b * 512 + i];
    a0 += f * gw[i];
    a1 += f * gw[512 + i];
  }
#pragma unroll
  for (int off = 32; off >= 1; off >>= 1) {
    a0 += __shfl_xor(a0, off);
    a1 += __shfl_xor(a1, off);
  }
  if (lane == 0) {
    float l0 = (a0 + gb[0] + noise[b * 2 + 0]) * (1.0f / 3.0f);
    float l1 = (a1 + gb[1] + noise[b * 2 + 1]) * (1.0f / 3.0f);
    float mm = fmaxf(l0, l1);
    float e0 = __expf(l0 - mm), e1 = __expf(l1 - mm);
    g1[b] = e1 / (e0 + e1);
  }
}

// ---------------------------------------------------------------------------
// f32 -> bf16 cast, 8 elems/thread, grid-stride (weights only)
// ---------------------------------------------------------------------------
__global__ __launch_bounds__(256) void cast_bf16_kernel(
    const float* __restrict__ in, unsigned short* __restrict__ out, int n8) {
  int i = blockIdx.x * blockDim.x + threadIdx.x;
  const int stride = gridDim.x * blockDim.x;
  for (; i < n8; i += stride) {
    const float4v* p = (const float4v*)(in + (size_t)i * 8);
    float4v v0 = p[0], v1 = p[1];
    ushort8 o = {f2b(v0[0]), f2b(v0[1]), f2b(v0[2]), f2b(v0[3]),
                 f2b(v1[0]), f2b(v1[1]), f2b(v1[2]), f2b(v1[3])};
    *(ushort8*)(out + (size_t)i * 8) = o;
  }
}

// ---------------------------------------------------------------------------
// bf16 GEMM: C[16384,1024] = A[16384,1024] @ W[1024,1024]^T + bias
// 256x256 tile, 8 waves, BK=32, 32 K-steps. Counted-vmcnt phase schedule,
// LDS XOR swizzle, setprio, XCD-chunked swizzle. Proven R11 schedule.
//
// A_F32=1 (R13): SAME schedule as R11 (lead-2 reg ring, write-side f2b),
// but the main loop is ROLLED in groups of 4 steps (period of the 2-ring x
// 4-ring slots) with LITERAL parity/slot macro args, instead of a 30-way
// full unroll. R11's #pragma unroll produced a ~30x150-instruction body
// that thrashed the 32KB I-cache -- counters showed NO pipe busy (MfmaUtil
// 21, VALU 17, HBM 8%) at ~4600 cyc/step, vs ~1500 cyc/step for the
// identical-structure rolled bf16 path. Register-ring indices stay
// compile-time literals (rule 20); schedule/waits byte-identical to R11.
// A_F32=0: gl_lds A with lead-3 4-ring (proven R4 path, rolled loop).
// A_BLOCKED: A in head-blocked layout [(b*16+h)][t][d]. OUT_F32==0 writes C
// head-blocked bf16 (feeds attn); OUT_F32==1 writes row-major f32.
// QSCALE folds attention 1/sqrt(d)=0.125 into the q-projection output.
// ---------------------------------------------------------------------------
#define AOFF(s) (A_BLOCKED ? (((s) >> 1) * 16384 + ((s)&1) * 32) : (s)*32)
#define STAGE_A(s)                                       \
  {                                                      \
    const unsigned short* _ap = abf + AOFF(s);           \
    unsigned short* d = &As[(s) & 3][wl];                \
    gl_lds16(_ap, d);                                    \
    gl_lds16(_ap + aD, d + 4096);                        \
  }
// P = literal parity of t ((t)&1)
#define ISSUE_A32(t, P)                                  \
  {                                                      \
    const float* _p = a32p + (size_t)(t) * 32;           \
    ar[P][0] = *(const float4v*)_p;                      \
    ar[P][1] = *(const float4v*)(_p + 4);                \
    ar[P][2] = *(const float4v*)(_p + 131072);           \
    ar[P][3] = *(const float4v*)(_p + 131072 + 4);       \
  }
#define WRITE_A32(P)                                                    \
  {                                                                     \
    float4v* v = ar[P];                                                 \
    uint4v h0 = {pack2(v[0][0], v[0][1]), pack2(v[0][2], v[0][3]),      \
                 pack2(v[1][0], v[1][1]), pack2(v[1][2], v[1][3])};     \
    uint4v h1 = {pack2(v[2][0], v[2][1]), pack2(v[2][2], v[2][3]),      \
                 pack2(v[3][0], v[3][1]), pack2(v[3][2], v[3][3])};     \
    unsigned short* d = &As[P][swA];                                    \
    *(uint4v*)d = h0;                                                   \
    *(uint4v*)(d + 4096) = h1;                                          \
  }
// SL = literal LDS slot
#define STAGE_B_SLOT(s, SL)                              \
  {                                                      \
    int k0s = (s) * 32;                                  \
    unsigned short* d = &Bs[SL][wl];                     \
    gl_lds16(b0p + k0s, d);                              \
    gl_lds16(b1p + k0s, d + 4096);                       \
  }
#define STAGE_B(s) STAGE_B_SLOT(s, (s)&3)
// f32-A step: PAR = (s)&1 literal, BS = (s)&3 literal
#define G32_STEP(s, PAR, BS, DO_IA, DO_SB, DO_W)                      \
  {                                                                   \
    const unsigned short* Ab = &As[PAR][0];                           \
    const unsigned short* Bb = &Bs[BS][0];                            \
    bf16x8 af[8], bfr[4];                                             \
    _Pragma("unroll") for (int mi = 0; mi < 8; ++mi)                  \
        af[mi] = *(const bf16x8*)&Ab[aoff + mi * 512];                \
    _Pragma("unroll") for (int ni = 0; ni < 2; ++ni)                  \
        bfr[ni] = *(const bf16x8*)&Bb[boff + ni * 512];               \
    if (DO_IA) ISSUE_A32((s) + 2, PAR);  /* (s+2)&1 == PAR */         \
    __builtin_amdgcn_s_barrier();                                     \
    __builtin_amdgcn_s_setprio(1);                                    \
    _Pragma("unroll") for (int mi = 0; mi < 8; ++mi) {                \
      acc[mi][0] = mfma16(af[mi], bfr[0], acc[mi][0]);                \
      acc[mi][1] = mfma16(af[mi], bfr[1], acc[mi][1]);                \
    }                                                                 \
    __builtin_amdgcn_s_setprio(0);                                    \
    __builtin_amdgcn_s_barrier();                                     \
    _Pragma("unroll") for (int ni = 2; ni < 4; ++ni)                  \
        bfr[ni] = *(const bf16x8*)&Bb[boff + ni * 512];               \
    if (DO_SB) STAGE_B_SLOT((s) + 3, ((BS) + 3) & 3);                 \
    __builtin_amdgcn_s_barrier();                                     \
    __builtin_amdgcn_s_setprio(1);                                    \
    _Pragma("unroll") for (int mi = 0; mi < 8; ++mi) {                \
      acc[mi][2] = mfma16(af[mi], bfr[2], acc[mi][2]);                \
      acc[mi][3] = mfma16(af[mi], bfr[3], acc[mi][3]);                \
    }                                                                 \
    __builtin_amdgcn_s_setprio(0);                                    \
    if (DO_W) WRITE_A32((PAR) ^ 1); /* writes A(s+1) */               \
  }
// bf16-A step (proven R4 path)
#define GEMM_STEP(s, DO_STAGE)                                        \
  {                                                                   \
    const unsigned short* Ab = &As[(s) & 3][0];                       \
    const unsigned short* Bb = &Bs[(s) & 3][0];                       \
    bf16x8 af[8], bfr[4];                                             \
    _Pragma("unroll") for (int mi = 0; mi < 8; ++mi)                  \
        af[mi] = *(const bf16x8*)&Ab[aoff + mi * 512];                \
    _Pragma("unroll") for (int ni = 0; ni < 2; ++ni)                  \
        bfr[ni] = *(const bf16x8*)&Bb[boff + ni * 512];               \
    if (DO_STAGE) STAGE_A((s) + 3);                                   \
    __builtin_amdgcn_s_barrier();                                     \
    __builtin_amdgcn_s_setprio(1);                                    \
    _Pragma("unroll") for (int mi = 0; mi < 8; ++mi) {                \
      acc[mi][0] = mfma16(af[mi], bfr[0], acc[mi][0]);                \
      acc[mi][1] = mfma16(af[mi], bfr[1], acc[mi][1]);                \
    }                                                                 \
    __builtin_amdgcn_s_setprio(0);                                    \
    __builtin_amdgcn_s_barrier();                                     \
    _Pragma("unroll") for (int ni = 2; ni < 4; ++ni)                  \
        bfr[ni] = *(const bf16x8*)&Bb[boff + ni * 512];               \
    if (DO_STAGE) STAGE_B((s) + 3);                                   \
    __builtin_amdgcn_s_barrier();                                     \
    __builtin_amdgcn_s_setprio(1);                                    \
    _Pragma("unroll") for (int mi = 0; mi < 8; ++mi) {                \
      acc[mi][2] = mfma16(af[mi], bfr[2], acc[mi][2]);                \
      acc[mi][3] = mfma16(af[mi], bfr[3], acc[mi][3]);                \
    }                                                                 \
    __builtin_amdgcn_s_setprio(0);                                    \
  }
#define STEP_WAIT(cntstr)                                \
  asm volatile("s_waitcnt " cntstr ::: "memory");        \
  __builtin_amdgcn_sched_barrier(0);                     \
  __builtin_amdgcn_s_barrier();

template <int OUT_F32, int QSCALE, int A_BLOCKED, int A_F32>
__global__ __launch_bounds__(512, 2) void gemm256_kernel(
    const void* __restrict__ Av, const unsigned short* __restrict__ W,
    const float* __restrict__ bias, void* __restrict__ Cv) {
  constexpr int K = 1024, N = 1024;
  __shared__ __attribute__((aligned(16))) unsigned short As[(A_F32 ? 2 : 4)][8192];
  __shared__ __attribute__((aligned(16))) unsigned short Bs[4][8192];  // 64 KB
  const int tid = threadIdx.x;
  const int wv = tid >> 6, lane = tid & 63;
  const int l15 = lane & 15, kg = lane >> 4;
  const int bid = blockIdx.x;
  const int cpx = gridDim.x >> 3;
  const int wg = (bid & 7) * cpx + (bid >> 3);
  const int m0 = (wg >> 2) * 256, n0 = (wg & 3) * 256;
  const int wmL = (wv >> 2) * 128, wnL = (wv & 3) * 64;

  const int sr = wv * 16 + (lane >> 2);                      // row in 128-half
  const int sc = ((lane & 3) * 8) ^ (((sr >> 1) & 3) << 3);  // pre-swizzled col
  const int srg = m0 + sr;
  const unsigned short* abf;  // bf16-A base (A_F32==0)
  if constexpr (A_BLOCKED)
    abf = (const unsigned short*)Av + (size_t)(srg & 63) * 262144 + (srg >> 6) * 64 + sc;
  else
    abf = (const unsigned short*)Av + (size_t)srg * K + sc;
  const int aD = A_BLOCKED ? 128 : 128 * K;
  // f32-A (A_F32==1): LINEAR source col; swizzle applied on the ds_write side
  const float* a32p = (const float*)Av + (size_t)srg * K + (lane & 3) * 8;
  const int swA = sr * 32 + (((lane & 3) ^ ((sr >> 1) & 3)) << 3);
  float4v ar[2][4];  // lead-2 reg ring (32 VGPR; literal-indexed)
  const unsigned short* b0p = W + (size_t)(n0 + sr) * K + sc;
  const unsigned short* b1p = b0p + (size_t)128 * K;
  const int wl = wv * 512;

  const int x = ((l15 >> 1) & 3) << 3;
  const int aoff = (wmL + l15) * 32 + ((kg * 8) ^ x);
  const int boff = (wnL + l15) * 32 + ((kg * 8) ^ x);

  f32x4 acc[8][4];
#pragma unroll
  for (int i = 0; i < 8; ++i)
#pragma unroll
    for (int j = 0; j < 4; ++j) acc[i][j] = (f32x4){0.f, 0.f, 0.f, 0.f};

  if constexpr (A_F32) {
    // Prologue (R11-proven): A(0),B(0),A(1),B(1),B(2); write A(0).
    // WRITE's compiler wait drains A(0); vmcnt(8) completes B(0).
    ISSUE_A32(0, 0); STAGE_B(0); ISSUE_A32(1, 1); STAGE_B(1); STAGE_B(2);
    WRITE_A32(0);
    STEP_WAIT("vmcnt(8) lgkmcnt(0)")
    // Rolled main loop: 7 x 4 steps (slot pattern period 4). Schedule
    // identical to R11's unrolled version; code stays I-cache-resident.
#pragma unroll 1
    for (int sb = 0; sb < 28; sb += 4) {
      G32_STEP(sb + 0, 0, 0, 1, 1, 1);
      STEP_WAIT("vmcnt(8) lgkmcnt(0)")
      G32_STEP(sb + 1, 1, 1, 1, 1, 1);
      STEP_WAIT("vmcnt(8) lgkmcnt(0)")
      G32_STEP(sb + 2, 0, 2, 1, 1, 1);
      STEP_WAIT("vmcnt(8) lgkmcnt(0)")
      G32_STEP(sb + 3, 1, 3, 1, 1, 1);
      STEP_WAIT("vmcnt(8) lgkmcnt(0)")
    }
    // Tail s=28..31 (28&1=0, 28&3=0); waits as in R11.
    G32_STEP(28, 0, 0, 1, 1, 1);
    STEP_WAIT("vmcnt(8) lgkmcnt(0)")
    G32_STEP(29, 1, 1, 1, 0, 1);  // issues A(31); writes A(30)
    STEP_WAIT("vmcnt(8) lgkmcnt(0)")
    G32_STEP(30, 0, 2, 0, 0, 1);  // writes A(31); compiler wait drains all
    STEP_WAIT("vmcnt(0) lgkmcnt(0)")
    G32_STEP(31, 1, 3, 0, 0, 0);
  } else {
    STAGE_A(0); STAGE_B(0); STAGE_A(1); STAGE_B(1); STAGE_A(2); STAGE_B(2);
    STEP_WAIT("vmcnt(8)")
    for (int s = 0; s < 29; ++s) {
      GEMM_STEP(s, 1);
      STEP_WAIT("vmcnt(8)")
    }
    GEMM_STEP(29, 0);
    STEP_WAIT("vmcnt(4)")
    GEMM_STEP(30, 0);
    STEP_WAIT("vmcnt(0)")
    GEMM_STEP(31, 0);
  }

#pragma unroll
  for (int mi = 0; mi < 8; ++mi) {
#pragma unroll
    for (int ni = 0; ni < 4; ++ni) {
      int col = n0 + wnL + ni * 16 + l15;
      float bcol = bias[col];
#pragma unroll
      for (int r = 0; r < 4; ++r) {
        int row = m0 + wmL + mi * 16 + kg * 4 + r;
        float v = acc[mi][ni][r] + bcol;
        if constexpr (QSCALE) v *= 0.125f;
        if constexpr (OUT_F32) {
          ((float*)Cv)[(size_t)row * N + col] = v;
        } else {
          // head-blocked store: [(b*16+h)][t][d]
          int t = row >> 6, bb = row & 63, hh = col >> 6, dd = col & 63;
          ((unsigned short*)Cv)[(size_t)((bb * 16 + hh) * 256 + t) * 64 + dd] = f2b(v);
        }
      }
    }
  }
}

// ---------------------------------------------------------------------------
// MFMA attention per (b,h) — EXACT R4-proven kernel.
// q/k/v/comb HEAD-BLOCKED [(b*16+h)][t][d]; 8 waves x 32 t-rows,
// strip-merged; natural-log softmax via __expf; pack2/f2b packing;
// T13 defer-rescale; V^T gran swizzle.
// combined = attn + g1[t>>2]*bw[b]*attn_pre (uses g0+g1==1).
// Q pre-scaled by 0.125 in the q-projection GEMM.
// ---------------------------------------------------------------------------
__global__ __launch_bounds__(512) void attn_kernel(
    const unsigned short* __restrict__ qb, const unsigned short* __restrict__ kb,
    const unsigned short* __restrict__ vb, const float* __restrict__ prefix,
    const float* __restrict__ bw, const float* __restrict__ g1,
    unsigned short* __restrict__ comb) {
  const int b = blockIdx.x, h = blockIdx.y;
  __shared__ __attribute__((aligned(16))) unsigned short Kl[256][64];    // 32 KB, chunk-XOR
  __shared__ __attribute__((aligned(16))) unsigned short Vt[64 * 256];   // 32 KB, V^T swizzled
  __shared__ __attribute__((aligned(16))) unsigned short PKl[16][64];    // 2 KB, chunk-XOR
  __shared__ __attribute__((aligned(16))) unsigned short PVt[64][32];    // 4 KB
  __shared__ __attribute__((aligned(16))) unsigned short Plds[8][16][40];// 10 KB, per-wave P
  unsigned short* Cb = &Kl[0][0];  // output bounce overlays Kl
  const int tid = threadIdx.x;
  const int wv = tid >> 6, lane = tid & 63;
  const size_t slab = (size_t)(b * NH + h) * 16384;

  // ---- staging (coalesced slab reads) ----
#pragma unroll
  for (int it = 0; it < 4; ++it) {
    int cid = tid + it * 512;
    int j = cid >> 3, c = cid & 7;  // j = s row, c = d-chunk
    gl_lds16(kb + slab + (size_t)j * 64 + ((c ^ (j & 7)) << 3),
             &Kl[0][0] + (size_t)(it * 512 + wv * 64) * 8);
    ushort8 vv = *(const ushort8*)(vb + slab + (size_t)j * 64 + (c << 3));
#pragma unroll
    for (int i = 0; i < 8; ++i) {  // V^T: (d=c*8+i, s=j); gran = (s>>3)^(d&7)^(d>>3)
      int gran = (j >> 3) ^ i ^ c;
      Vt[(c * 8 + i) * 256 + gran * 8 + (j & 7)] = vv[i];
    }
  }
  if (tid < 256) {
    int arr = tid >> 7, cid = tid & 127;
    int sp = cid >> 3, c = cid & 7;
    const float* src = prefix + ((size_t)(b * 2 + arr) * PP + sp) * EMB + h * HD + c * 8;
    float4v v0 = *(const float4v*)src;
    float4v v1 = *(const float4v*)(src + 4);
    if (arr == 0) {
      ushort8 o = {f2b(v0[0]), f2b(v0[1]), f2b(v0[2]), f2b(v0[3]),
                   f2b(v1[0]), f2b(v1[1]), f2b(v1[2]), f2b(v1[3])};
      *(ushort8*)&PKl[sp][((c ^ (sp & 7)) << 3)] = o;
    } else {
#pragma unroll
      for (int i = 0; i < 8; ++i)
        PVt[c * 8 + i][sp] = f2b(i < 4 ? v0[i] : v1[i - 4]);
    }
  } else if (tid < 384) {
    int cid = tid - 256;
    *(ushort8*)&PVt[cid >> 1][16 + (cid & 1) * 8] = (ushort8){0, 0, 0, 0, 0, 0, 0, 0};
  }
  __syncthreads();

  const int l15 = lane & 15, g = lane >> 4;
  const int swl = l15 & 7;
  const float bwb = bw[b];
  unsigned short(&Pw)[16][40] = Plds[wv];

  const int t0 = wv * 32 + l15;  // strip-0 row; strip-1 = t0+16
  const size_t qbase = slab + (size_t)t0 * 64;
  bf16x8 qf[2][2];
  qf[0][0] = *(const bf16x8*)(qb + qbase + g * 8);
  qf[0][1] = *(const bf16x8*)(qb + qbase + 32 + g * 8);
  qf[1][0] = *(const bf16x8*)(qb + qbase + 1024 + g * 8);
  qf[1][1] = *(const bf16x8*)(qb + qbase + 1024 + 32 + g * 8);

  f32x4 O[2][4];
#pragma unroll
  for (int st = 0; st < 2; ++st)
#pragma unroll
    for (int dt = 0; dt < 4; ++dt) O[st][dt] = (f32x4){0.f, 0.f, 0.f, 0.f};
  float m[2] = {-3.0e38f, -3.0e38f}, l[2] = {0.f, 0.f};

#pragma unroll
  for (int ch = 0; ch < 8; ++ch) {  // 32 s per chunk
    const int rA = ch * 32 + l15, rB = rA + 16;
    bf16x8 ka0 = *(const bf16x8*)&Kl[rA][((g ^ swl) << 3)];
    bf16x8 ka1 = *(const bf16x8*)&Kl[rA][(((4 + g) ^ swl) << 3)];
    bf16x8 kb0 = *(const bf16x8*)&Kl[rB][((g ^ swl) << 3)];
    bf16x8 kb1 = *(const bf16x8*)&Kl[rB][(((4 + g) ^ swl) << 3)];
    f32x4 s[2][2];
#pragma unroll
    for (int st = 0; st < 2; ++st) {
      s[st][0] = (f32x4){0.f, 0.f, 0.f, 0.f};
      s[st][1] = (f32x4){0.f, 0.f, 0.f, 0.f};
      s[st][0] = mfma16(ka0, qf[st][0], s[st][0]);
      s[st][0] = mfma16(ka1, qf[st][1], s[st][0]);
      s[st][1] = mfma16(kb0, qf[st][0], s[st][1]);
      s[st][1] = mfma16(kb1, qf[st][1], s[st][1]);
    }
    bf16x8 pf[2];
#pragma unroll
    for (int st = 0; st < 2; ++st) {
      f32x4 sa = s[st][0], sb = s[st][1];
      float mx = fmaxf(fmaxf(fmaxf(sa[0], sa[1]), fmaxf(sa[2], sa[3])),
                       fmaxf(fmaxf(sb[0], sb[1]), fmaxf(sb[2], sb[3])));
      mx = fmaxf(mx, __shfl_xor(mx, 16));
      mx = fmaxf(mx, __shfl_xor(mx, 32));
      // T13 defer-rescale: only rescale when some row grew by > 8
      if (__ballot(mx > m[st] + 8.0f) != 0ull) {
        float mn = fmaxf(m[st], mx);
        float f = __expf(m[st] - mn);
        m[st] = mn;
        l[st] *= f;
#pragma unroll
        for (int dt = 0; dt < 4; ++dt)
#pragma unroll
          for (int r = 0; r < 4; ++r) O[st][dt][r] *= f;
      }
      float pA[4], pB[4];
#pragma unroll
      for (int r = 0; r < 4; ++r) {
        pA[r] = __expf(sa[r] - m[st]);
        pB[r] = __expf(sb[r] - m[st]);
      }
      uint2v wa = {pack2(pA[0], pA[1]), pack2(pA[2], pA[3])};
      uint2v wb2 = {pack2(pB[0], pB[1]), pack2(pB[2], pB[3])};
      *(uint2v*)&Pw[l15][g * 4] = wa;
      *(uint2v*)&Pw[l15][16 + g * 4] = wb2;
      // l accumulates the ROUNDED p so normalization compensates quantization
      float sloc = b2f((unsigned short)(wa[0] & 0xffff)) + b2f((unsigned short)(wa[0] >> 16)) +
                   b2f((unsigned short)(wa[1] & 0xffff)) + b2f((unsigned short)(wa[1] >> 16)) +
                   b2f((unsigned short)(wb2[0] & 0xffff)) + b2f((unsigned short)(wb2[0] >> 16)) +
                   b2f((unsigned short)(wb2[1] & 0xffff)) + b2f((unsigned short)(wb2[1] >> 16));
      l[st] += sloc;
      // read own B-frag before next strip overwrites the tile (in-order DS)
      pf[st] = *(const bf16x8*)&Pw[l15][g * 8];
    }
#pragma unroll
    for (int dt = 0; dt < 4; ++dt) {
      const int drow = dt * 16 + l15;
      const int gran = (ch * 4 + g) ^ (drow & 7) ^ (drow >> 3);
      bf16x8 vf = *(const bf16x8*)&Vt[drow * 256 + gran * 8];
      O[0][dt] = mfma16(vf, pf[0], O[0][dt]);
      O[1][dt] = mfma16(vf, pf[1], O[1][dt]);
    }
  }

#pragma unroll
  for (int st = 0; st < 2; ++st) {
    float lf = l[st];
    lf += __shfl_xor(lf, 16);
    lf += __shfl_xor(lf, 32);
    float inv = 1.0f / lf;
#pragma unroll
    for (int dt = 0; dt < 4; ++dt)
#pragma unroll
      for (int r = 0; r < 4; ++r) O[st][dt][r] *= inv;
  }

  // prefix attention (s=16 zero-padded to 32), scaled by g1*bw/sum
  {
    bf16x8 pk0 = *(const bf16x8*)&PKl[l15][((g ^ swl) << 3)];
    bf16x8 pk1 = *(const bf16x8*)&PKl[l15][(((4 + g) ^ swl) << 3)];
    bf16x8 ppf[2];
#pragma unroll
    for (int st = 0; st < 2; ++st) {
      f32x4 sp4 = (f32x4){0.f, 0.f, 0.f, 0.f};
      sp4 = mfma16(pk0, qf[st][0], sp4);
      sp4 = mfma16(pk1, qf[st][1], sp4);
      float pm = fmaxf(fmaxf(sp4[0], sp4[1]), fmaxf(sp4[2], sp4[3]));
      pm = fmaxf(pm, __shfl_xor(pm, 16));
      pm = fmaxf(pm, __shfl_xor(pm, 32));
      float pe[4], pl = 0.f;
#pragma unroll
      for (int r = 0; r < 4; ++r) {
        pe[r] = __expf(sp4[r] - pm);
        pl += pe[r];
      }
      pl += __shfl_xor(pl, 16);
      pl += __shfl_xor(pl, 32);
      float cpre = g1[(t0 + 16 * st) >> 2] * bwb / pl;
#pragma unroll
      for (int r = 0; r < 4; ++r) pe[r] *= cpre;
      *(uint2v*)&Pw[l15][g * 4] = (uint2v){pack2(pe[0], pe[1]), pack2(pe[2], pe[3])};
      *(uint2v*)&Pw[l15][16 + g * 4] = (uint2v){0u, 0u};
      ppf[st] = *(const bf16x8*)&Pw[l15][g * 8];
    }
#pragma unroll
    for (int dt = 0; dt < 4; ++dt) {
      bf16x8 pvf = *(const bf16x8*)&PVt[dt * 16 + l15][g * 8];
      O[0][dt] = mfma16(pvf, ppf[0], O[0][dt]);
      O[1][dt] = mfma16(pvf, ppf[1], O[1][dt]);
    }
  }

  __syncthreads();  // all waves done reading Kl before bounce overlays it
#pragma unroll
  for (int st = 0; st < 2; ++st) {
    int t = wv * 32 + st * 16 + l15;
#pragma unroll
    for (int dt = 0; dt < 4; ++dt) {
#pragma unroll
      for (int u = 0; u < 2; ++u) {
        unsigned int pw = pack2(O[st][dt][2 * u], O[st][dt][2 * u + 1]);
        int d = dt * 16 + g * 4 + 2 * u;
        *(unsigned int*)&Cb[t * 64 + (((d >> 3) ^ (t & 7)) << 3) + (d & 7)] = pw;
      }
    }
  }
  __syncthreads();
#pragma unroll
  for (int it = 0; it < 4; ++it) {
    int cid = tid + it * 512;
    int j = cid >> 3, c = cid & 7;
    ushort8 row = *(const ushort8*)&Cb[j * 64 + ((c ^ (j & 7)) << 3)];
    *(ushort8*)(comb + slab + (size_t)j * 64 + (c << 3)) = row;
  }
}

// ---------------------------------------------------------------------------
extern "C" void kernel_launch(void* const* d_in, const int* in_sizes, int n_in,
                              void* d_out, int out_size, void* d_ws, size_t ws_size,
                              hipStream_t stream) {
  const float* query = (const float*)d_in[1];
  const float* key = (const float*)d_in[2];
  const float* value = (const float*)d_in[3];
  const float* prefix = (const float*)d_in[4];
  const float* bw = (const float*)d_in[5];
  const float* feat = (const float*)d_in[6];
  const float* noise = (const float*)d_in[7];
  const float* ipw = (const float*)d_in[8];
  const float* ipb = (const float*)d_in[9];
  const float* outw = (const float*)d_in[10];
  const float* outb = (const float*)d_in[11];
  const float* gw = (const float*)d_in[12];
  const float* gb = (const float*)d_in[13];
  float* out = (float*)d_out;

  char* ws = (char*)d_ws;
  const size_t MATB = (size_t)16384 * 1024;  // elements per [16384,1024] matrix
  unsigned short* qb = (unsigned short*)ws;
  unsigned short* kb = qb + MATB;
  unsigned short* vb = kb + MATB;
  unsigned short* cb = vb + MATB;            // attn output (head-blocked)
  unsigned short* wip = cb + MATB;           // bf16 in_proj_w [3072,1024]
  unsigned short* wo = wip + (size_t)3072 * 1024;  // bf16 out_w [1024,1024]
  float* g1 = (float*)(wo + (size_t)1024 * 1024);

  gate_kernel<<<64, 64, 0, stream>>>(feat, gw, gb, noise, g1);

  // weight casts only (16.8 MB total)
  cast_bf16_kernel<<<1536, 256, 0, stream>>>(ipw, wip, 3072 * 1024 / 8);
  cast_bf16_kernel<<<512, 256, 0, stream>>>(outw, wo, 1024 * 1024 / 8);

  // projections read f32 inputs directly (f2b write-side staging, lead-2,
  // rolled main loop)
  gemm256_kernel<0, 1, 0, 1><<<256, 512, 0, stream>>>(query, wip, ipb, qb);
  gemm256_kernel<0, 0, 0, 1><<<256, 512, 0, stream>>>(key, wip + (size_t)1024 * 1024, ipb + 1024, kb);
  gemm256_kernel<0, 0, 0, 1><<<256, 512, 0, stream>>>(value, wip + (size_t)2048 * 1024, ipb + 2048, vb);

  attn_kernel<<<dim3(64, 16), 512, 0, stream>>>(qb, kb, vb, prefix, bw, g1, cb);

  // out-projection reads head-blocked bf16 attn output (proven gl_lds path)
  gemm256_kernel<1, 0, 1, 0><<<256, 512, 0, stream>>>(cb, wo, outb, out);
}